// Round 1
// baseline (3990.055 us; speedup 1.0000x reference)
//
#include <hip/hip_runtime.h>
#include <math.h>

#define B 64
#define T 20
#define C 512
#define HW 196
#define V 10000
#define E 256
#define U 512
#define G4U (4*U)       // 2048
#define XDIM (E + C)    // 768
#define ODIM (U + C + E) // 1280

// ---------- feats_mean[b][c] = mean_k img[b][c][k] ----------
__global__ void k_mean(const float* __restrict__ img, float* __restrict__ fm) {
    int wave = threadIdx.x >> 6;
    int lane = threadIdx.x & 63;
    int row = blockIdx.x * 4 + wave;          // row in [0, B*C)
    const float* p = img + (size_t)row * HW;
    float s = p[lane] + p[lane + 64] + p[lane + 128];
    if (lane < 4) s += p[lane + 192];
    for (int off = 32; off > 0; off >>= 1) s += __shfl_down(s, off, 64);
    if (lane == 0) fm[row] = s * (1.0f / HW);
}

// ---------- hid0 / cell0 ----------
__global__ void k_init(const float* __restrict__ fm,
                       const float* __restrict__ W_h0, const float* __restrict__ b_h0,
                       const float* __restrict__ W_c0, const float* __restrict__ b_c0,
                       float* __restrict__ hid, float* __restrict__ cell) {
    int idx = blockIdx.x * 256 + threadIdx.x;   // [0, 2*B*U)
    int which = idx / (B * U);
    int r = idx % (B * U);
    int b = r / U, u = r % U;
    const float* W = which ? W_c0 : W_h0;
    const float* bias = which ? b_c0 : b_h0;
    const float* f = fm + b * C;
    const float* w = W + (size_t)u * C;
    float s = bias[u];
    for (int c = 0; c < C; c++) s += f[c] * w[c];
    if (which) cell[r] = s; else hid[r] = s;
}

// ---------- keysT[b][u][k] = b_key[u] + sum_c W_key[u][c] * img[b][c][k] ----------
__global__ void k_keys(const float* __restrict__ img, const float* __restrict__ W_key,
                       const float* __restrict__ b_key, float* __restrict__ keysT) {
    __shared__ float Ws[8 * C];     // 16 KB
    int b = blockIdx.x / (U / 8);
    int u0 = (blockIdx.x % (U / 8)) * 8;
    for (int i = threadIdx.x; i < 8 * C; i += 512)
        Ws[i] = W_key[(size_t)u0 * C + i];
    __syncthreads();
    int wave = threadIdx.x >> 6, lane = threadIdx.x & 63;
    int u = u0 + wave;
    const float4* imgb = (const float4*)(img + (size_t)b * C * HW);
    if (lane < 49) {                 // 49 float4 = 196 floats per row
        float4 acc = {0.f, 0.f, 0.f, 0.f};
        for (int c = 0; c < C; c++) {
            float w = Ws[wave * C + c];
            float4 v = imgb[c * 49 + lane];
            acc.x += w * v.x; acc.y += w * v.y; acc.z += w * v.z; acc.w += w * v.w;
        }
        float bk = b_key[u];
        acc.x += bk; acc.y += bk; acc.z += bk; acc.w += bk;
        float4* kp = (float4*)(keysT + ((size_t)b * U + u) * HW);
        kp[lane] = acc;
    }
}

// ---------- embedding gather + max_norm renorm; also fills emb part of outs ----------
__global__ void k_emb(const int* __restrict__ ix, const float* __restrict__ emb,
                      float* __restrict__ cap_emb, float* __restrict__ outs) {
    int bt = blockIdx.x;          // [0, B*T)
    int e = threadIdx.x;          // 256
    int row = ix[bt];
    float v = emb[(size_t)row * E + e];
    __shared__ float red[4];
    float sq = v * v;
    for (int off = 32; off > 0; off >>= 1) sq += __shfl_down(sq, off, 64);
    int wave = e >> 6, lane = e & 63;
    if (lane == 0) red[wave] = sq;
    __syncthreads();
    float norm = sqrtf(red[0] + red[1] + red[2] + red[3]);
    float scale = fminf(1.0f, 5.0f / fmaxf(norm, 1e-12f));
    v *= scale;
    cap_emb[(size_t)bt * E + e] = v;
    outs[(size_t)bt * ODIM + (U + C) + e] = v;
}

// ---------- one attention step: scores -> softmax -> context a ----------
__global__ void k_attn(const float* __restrict__ hid, const float* __restrict__ keysT,
                       const float* __restrict__ img, float* __restrict__ a_buf,
                       float* __restrict__ outs, float* __restrict__ attn_out, int t) {
    int b = blockIdx.x;
    int tid = threadIdx.x;
    __shared__ float hidS[U];
    __shared__ float wS[256];
    __shared__ float red[4];
    hidS[tid]       = hid[b * U + tid];
    hidS[tid + 256] = hid[b * U + tid + 256];
    __syncthreads();

    float sc = 0.0f;
    float s = -1e30f;
    if (tid < HW) {
        const float* kp = keysT + (size_t)b * U * HW + tid;
        float acc = 0.f;
        for (int u = 0; u < U; u++) acc += hidS[u] * kp[u * HW];
        sc = acc * 0.044194173824159216f;   // 1/sqrt(512)
        s = sc;
    }
    // block max
    float m = s;
    for (int off = 32; off > 0; off >>= 1) m = fmaxf(m, __shfl_down(m, off, 64));
    int wave = tid >> 6, lane = tid & 63;
    if (lane == 0) red[wave] = m;
    __syncthreads();
    m = fmaxf(fmaxf(red[0], red[1]), fmaxf(red[2], red[3]));
    float ex = (tid < HW) ? expf(sc - m) : 0.0f;
    float ssum = ex;
    for (int off = 32; off > 0; off >>= 1) ssum += __shfl_down(ssum, off, 64);
    __syncthreads();
    if (lane == 0) red[wave] = ssum;
    __syncthreads();
    ssum = red[0] + red[1] + red[2] + red[3];
    float w = ex / ssum;
    wS[tid] = w;
    if (tid < HW) attn_out[((size_t)b * T + t) * HW + tid] = w;
    __syncthreads();

    // a[b][c] = sum_k w[k] * img[b][c][k]
    const float4* imgb = (const float4*)(img + (size_t)b * C * HW);
    float* orow = outs + ((size_t)b * T + t) * ODIM + U;
    for (int c = tid; c < C; c += 256) {
        const float4* r4 = imgb + c * 49;
        float acc = 0.f;
        for (int k4 = 0; k4 < 49; k4++) {
            float4 v = r4[k4];
            acc += wS[k4 * 4 + 0] * v.x + wS[k4 * 4 + 1] * v.y
                 + wS[k4 * 4 + 2] * v.z + wS[k4 * 4 + 3] * v.w;
        }
        a_buf[b * C + c] = acc;
        orow[c] = acc;
    }
}

// ---------- gates = x @ W_ih^T + b_ih + hid @ W_hh^T + b_hh ----------
__global__ void k_gates(const float* __restrict__ cap_emb, const float* __restrict__ a_buf,
                        const float* __restrict__ hid,
                        const float* __restrict__ W_ih, const float* __restrict__ b_ih,
                        const float* __restrict__ W_hh, const float* __restrict__ b_hh,
                        float* __restrict__ gates, int t) {
    int j = blockIdx.x * 4 + (threadIdx.x >> 6);   // [0, 2048)
    int b = threadIdx.x & 63;
    const float* wi = W_ih + (size_t)j * XDIM;
    const float* wh = W_hh + (size_t)j * U;
    const float* xe = cap_emb + ((size_t)b * T + t) * E;
    const float* xa = a_buf + b * C;
    const float* xh = hid + b * U;
    float acc = b_ih[j] + b_hh[j];
    for (int e = 0; e < E; e++) acc += wi[e] * xe[e];
    for (int c = 0; c < C; c++) acc += wi[E + c] * xa[c];
    for (int u = 0; u < U; u++) acc += wh[u] * xh[u];
    gates[b * G4U + j] = acc;
}

// ---------- LSTM pointwise update; writes hid part of outs ----------
__global__ void k_point(const float* __restrict__ gates, float* __restrict__ hid,
                        float* __restrict__ cell, float* __restrict__ outs, int t) {
    int idx = blockIdx.x * 256 + threadIdx.x;  // [0, B*U)
    int b = idx / U, u = idx % U;
    const float* g = gates + (size_t)b * G4U;
    float gi = g[u], gf = g[U + u], gg = g[2 * U + u], go = g[3 * U + u];
    float si = 1.0f / (1.0f + expf(-gi));
    float sf = 1.0f / (1.0f + expf(-gf));
    float so = 1.0f / (1.0f + expf(-go));
    float tg = tanhf(gg);
    float c_new = sf * cell[idx] + si * tg;
    float h_new = so * tanhf(c_new);
    cell[idx] = c_new;
    hid[idx] = h_new;
    outs[((size_t)b * T + t) * ODIM + u] = h_new;
}

// ---------- logits = outs @ W_out^T + b_out : [1280,1280] x [10000,1280]^T ----------
#define TK 32
__global__ __launch_bounds__(256) void k_logits(const float* __restrict__ A,
                                                const float* __restrict__ Wo,
                                                const float* __restrict__ bo,
                                                float* __restrict__ Cout) {
    int n0 = blockIdx.x * 64;
    int m0 = blockIdx.y * 64;
    __shared__ float As[TK][68];
    __shared__ float Bs[TK][68];
    int tid = threadIdx.x;
    int tx = tid & 15, ty = tid >> 4;
    float acc[4][4] = {};
    for (int k0 = 0; k0 < ODIM; k0 += TK) {
        for (int i = 0; i < 8; i++) {
            int idx = tid + i * 256;          // 0..2047
            int r = idx >> 5, kk = idx & 31;
            As[kk][r] = A[(size_t)(m0 + r) * ODIM + k0 + kk];
            int n = n0 + r;
            Bs[kk][r] = (n < V) ? Wo[(size_t)n * ODIM + k0 + kk] : 0.0f;
        }
        __syncthreads();
        for (int kk = 0; kk < TK; kk++) {
            float4 av = *(const float4*)&As[kk][ty * 4];
            float4 bv = *(const float4*)&Bs[kk][tx * 4];
            float a_[4] = {av.x, av.y, av.z, av.w};
            float b_[4] = {bv.x, bv.y, bv.z, bv.w};
            #pragma unroll
            for (int i = 0; i < 4; i++)
                #pragma unroll
                for (int j = 0; j < 4; j++)
                    acc[i][j] += a_[i] * b_[j];
        }
        __syncthreads();
    }
    int nb = n0 + tx * 4;
    if (nb + 3 < V) {
        float4 bias4 = *(const float4*)&bo[nb];
        #pragma unroll
        for (int i = 0; i < 4; i++) {
            int m = m0 + ty * 4 + i;
            float4 r4;
            r4.x = acc[i][0] + bias4.x;
            r4.y = acc[i][1] + bias4.y;
            r4.z = acc[i][2] + bias4.z;
            r4.w = acc[i][3] + bias4.w;
            *(float4*)&Cout[(size_t)m * V + nb] = r4;
        }
    }
}

extern "C" void kernel_launch(void* const* d_in, const int* in_sizes, int n_in,
                              void* d_out, int out_size, void* d_ws, size_t ws_size,
                              hipStream_t stream) {
    const float* img   = (const float*)d_in[0];
    const int*   capix = (const int*)d_in[1];
    const float* W_h0  = (const float*)d_in[2];
    const float* b_h0  = (const float*)d_in[3];
    const float* W_c0  = (const float*)d_in[4];
    const float* b_c0  = (const float*)d_in[5];
    const float* emb   = (const float*)d_in[6];
    const float* W_key = (const float*)d_in[7];
    const float* b_key = (const float*)d_in[8];
    const float* W_ih  = (const float*)d_in[9];
    const float* b_ih  = (const float*)d_in[10];
    const float* W_hh  = (const float*)d_in[11];
    const float* b_hh  = (const float*)d_in[12];
    const float* W_out = (const float*)d_in[13];
    const float* b_out = (const float*)d_in[14];

    float* ws = (float*)d_ws;
    float* fm      = ws;                    // B*C      = 32768
    float* hid     = fm + 32768;            // B*U      = 32768
    float* cell    = hid + 32768;           // B*U      = 32768
    float* a_buf   = cell + 32768;          // B*C      = 32768
    float* gates   = a_buf + 32768;         // B*4U     = 131072
    float* cap_emb = gates + 131072;        // B*T*E    = 327680
    float* outs    = cap_emb + 327680;      // B*T*1280 = 1638400
    float* keysT   = outs + 1638400;        // B*U*HW   = 6422528

    float* logits = (float*)d_out;                    // [B,T,V]
    float* attn   = logits + (size_t)B * T * V;       // [B,T,HW]

    k_mean<<<(B * C) / 4, 256, 0, stream>>>(img, fm);
    k_init<<<(2 * B * U) / 256, 256, 0, stream>>>(fm, W_h0, b_h0, W_c0, b_c0, hid, cell);
    k_keys<<<B * (U / 8), 512, 0, stream>>>(img, W_key, b_key, keysT);
    k_emb<<<B * T, 256, 0, stream>>>(capix, emb, cap_emb, outs);

    for (int t = 0; t < T; t++) {
        k_attn<<<B, 256, 0, stream>>>(hid, keysT, img, a_buf, outs, attn, t);
        k_gates<<<G4U / 4, 256, 0, stream>>>(cap_emb, a_buf, hid, W_ih, b_ih, W_hh, b_hh, gates, t);
        k_point<<<(B * U) / 256, 256, 0, stream>>>(gates, hid, cell, outs, t);
    }

    k_logits<<<dim3((V + 63) / 64, (B * T) / 64), 256, 0, stream>>>(outs, W_out, b_out, logits);
}

// Round 2
// 2746.958 us; speedup vs baseline: 1.4525x; 1.4525x over previous
//
#include <hip/hip_runtime.h>
#include <math.h>

#define B 64
#define T 20
#define C 512
#define HW 196
#define V 10000
#define E 256
#define U 512
#define G4U 2048
#define ODIM 1280   // U + C + E
#define KTOT 1280   // E + C + U (gates reduction dim)

// ---------- feats_mean[b][c] = mean_k img[b][c][k] ----------
__global__ void k_mean(const float* __restrict__ img, float* __restrict__ fm) {
    int wave = threadIdx.x >> 6;
    int lane = threadIdx.x & 63;
    int row = blockIdx.x * 4 + wave;          // row in [0, B*C)
    const float* p = img + (size_t)row * HW;
    float s = p[lane] + p[lane + 64] + p[lane + 128];
    if (lane < 4) s += p[lane + 192];
    for (int off = 32; off > 0; off >>= 1) s += __shfl_down(s, off, 64);
    if (lane == 0) fm[row] = s * (1.0f / HW);
}

// ---------- hid0 / cell0 : one wave per output, lane-parallel dot ----------
__global__ void k_init(const float* __restrict__ fm,
                       const float* __restrict__ W_h0, const float* __restrict__ b_h0,
                       const float* __restrict__ W_c0, const float* __restrict__ b_c0,
                       float* __restrict__ hid, float* __restrict__ cell) {
    int wv = blockIdx.x * 4 + (threadIdx.x >> 6);   // [0, 2*B*U)
    int lane = threadIdx.x & 63;
    int which = wv >> 15;          // B*U = 32768
    int r = wv & 32767;
    int b = r >> 9, u = r & 511;
    const float* W = which ? W_c0 : W_h0;
    const float* bias = which ? b_c0 : b_h0;
    const float* f = fm + b * C;
    const float* w = W + (size_t)u * C;
    float s = 0.f;
    #pragma unroll
    for (int c = 0; c < C; c += 64) s += f[c + lane] * w[c + lane];
    for (int off = 32; off > 0; off >>= 1) s += __shfl_down(s, off, 64);
    if (lane == 0) {
        float v = s + bias[u];
        if (which) cell[r] = v; else hid[r] = v;
    }
}

// ---------- keysT[b][u][k] = b_key[u] + sum_c W_key[u][c] * img[b][c][k] ----------
__global__ void k_keys(const float* __restrict__ img, const float* __restrict__ W_key,
                       const float* __restrict__ b_key, float* __restrict__ keysT) {
    __shared__ float Ws[8 * C];     // 16 KB
    int b = blockIdx.x / (U / 8);
    int u0 = (blockIdx.x % (U / 8)) * 8;
    for (int i = threadIdx.x; i < 8 * C; i += 512)
        Ws[i] = W_key[(size_t)u0 * C + i];
    __syncthreads();
    int wave = threadIdx.x >> 6, lane = threadIdx.x & 63;
    int u = u0 + wave;
    const float4* imgb = (const float4*)(img + (size_t)b * C * HW);
    if (lane < 49) {                 // 49 float4 = 196 floats per row
        float4 acc = {0.f, 0.f, 0.f, 0.f};
        for (int c = 0; c < C; c++) {
            float w = Ws[wave * C + c];
            float4 v = imgb[c * 49 + lane];
            acc.x += w * v.x; acc.y += w * v.y; acc.z += w * v.z; acc.w += w * v.w;
        }
        float bk = b_key[u];
        acc.x += bk; acc.y += bk; acc.z += bk; acc.w += bk;
        float4* kp = (float4*)(keysT + ((size_t)b * U + u) * HW);
        kp[lane] = acc;
    }
}

// ---------- embedding gather + max_norm renorm -> outs emb slot ----------
__global__ void k_emb(const int* __restrict__ ix, const float* __restrict__ emb,
                      float* __restrict__ outs) {
    int bt = blockIdx.x;          // [0, B*T)
    int e = threadIdx.x;          // 256
    int row = ix[bt];
    float v = emb[(size_t)row * E + e];
    __shared__ float red[4];
    float sq = v * v;
    for (int off = 32; off > 0; off >>= 1) sq += __shfl_down(sq, off, 64);
    int wave = e >> 6, lane = e & 63;
    if (lane == 0) red[wave] = sq;
    __syncthreads();
    float norm = sqrtf(red[0] + red[1] + red[2] + red[3]);
    float scale = fminf(1.0f, 5.0f / fmaxf(norm, 1e-12f));
    v *= scale;
    outs[(size_t)bt * ODIM + (U + C) + e] = v;
}

// ---------- one attention step: scores -> softmax -> context a (into outs) ----------
__global__ void k_attn(const float* __restrict__ hid, const float* __restrict__ keysT,
                       const float* __restrict__ img,
                       float* __restrict__ outs, float* __restrict__ attn_out, int t) {
    int b = blockIdx.x;
    int tid = threadIdx.x;
    __shared__ float hidS[U];
    __shared__ float wS[256];
    __shared__ float red[4];
    hidS[tid]       = hid[b * U + tid];
    hidS[tid + 256] = hid[b * U + tid + 256];
    __syncthreads();

    float sc = 0.0f;
    float s = -1e30f;
    if (tid < HW) {
        const float* kp = keysT + (size_t)b * U * HW + tid;
        float acc = 0.f;
        for (int u = 0; u < U; u++) acc += hidS[u] * kp[u * HW];
        sc = acc * 0.044194173824159216f;   // 1/sqrt(512)
        s = sc;
    }
    float m = s;
    for (int off = 32; off > 0; off >>= 1) m = fmaxf(m, __shfl_down(m, off, 64));
    int wave = tid >> 6, lane = tid & 63;
    if (lane == 0) red[wave] = m;
    __syncthreads();
    m = fmaxf(fmaxf(red[0], red[1]), fmaxf(red[2], red[3]));
    float ex = (tid < HW) ? expf(sc - m) : 0.0f;
    float ssum = ex;
    for (int off = 32; off > 0; off >>= 1) ssum += __shfl_down(ssum, off, 64);
    __syncthreads();
    if (lane == 0) red[wave] = ssum;
    __syncthreads();
    ssum = red[0] + red[1] + red[2] + red[3];
    float w = ex / ssum;
    wS[tid] = w;
    if (tid < HW) attn_out[((size_t)b * T + t) * HW + tid] = w;
    __syncthreads();

    // a[b][c] = sum_k w[k] * img[b][c][k]  -> outs a-slot
    const float4* imgb = (const float4*)(img + (size_t)b * C * HW);
    float* orow = outs + ((size_t)b * T + t) * ODIM + U;
    for (int c = tid; c < C; c += 256) {
        const float4* r4 = imgb + c * 49;
        float acc = 0.f;
        for (int k4 = 0; k4 < 49; k4++) {
            float4 v = r4[k4];
            acc += wS[k4 * 4 + 0] * v.x + wS[k4 * 4 + 1] * v.y
                 + wS[k4 * 4 + 2] * v.z + wS[k4 * 4 + 3] * v.w;
        }
        orow[c] = acc;
    }
}

// ---------- gates GEMM: partial[ks][b][j] = sum_{k in slice} x[b][k] * W[j][k]
// x[b] = [emb_t (outs col 1024+) | a (outs col 512+) | hid_prev]
// W[j] = [W_ih[j][0:768] | W_hh[j][0:512]]
// tile 64b x 32j, K-split 4 (slice 320 = 10 chunks of 32)
__global__ __launch_bounds__(256) void k_gates2(
    const float* __restrict__ outs, const float* __restrict__ hid,
    const float* __restrict__ W_ih, const float* __restrict__ W_hh,
    float* __restrict__ partials, int t) {
    __shared__ float As[32][68];   // [kk][b]
    __shared__ float Bs[32][36];   // [kk][j_local]
    int j0 = blockIdx.x * 32;
    int ks = blockIdx.y;           // 0..3
    int tid = threadIdx.x;
    int tx = tid & 15;             // j pair
    int ty = tid >> 4;             // b quad
    float acc[4][2] = {};
    for (int c = 0; c < 10; c++) {
        int k0 = ks * 320 + c * 32;
        #pragma unroll
        for (int i = 0; i < 8; i++) {
            int idx = tid + i * 256;
            int r = idx >> 5, kk = idx & 31;
            int k = k0 + kk;
            float v;
            if (k < 256)      v = outs[((size_t)r * T + t) * ODIM + 1024 + k];
            else if (k < 768) v = outs[((size_t)r * T + t) * ODIM + 256 + k]; // = 512 + (k-256)
            else              v = hid[r * U + (k - 768)];
            As[kk][r] = v;
        }
        #pragma unroll
        for (int i = 0; i < 4; i++) {
            int idx = tid + i * 256;
            int r = idx >> 5, kk = idx & 31;
            int j = j0 + r;
            int k = k0 + kk;
            float v;
            if (k < 768) v = W_ih[(size_t)j * 768 + k];
            else         v = W_hh[(size_t)j * 512 + (k - 768)];
            Bs[kk][r] = v;
        }
        __syncthreads();
        #pragma unroll
        for (int kk = 0; kk < 32; kk++) {
            float4 av = *(const float4*)&As[kk][ty * 4];
            float2 bv = *(const float2*)&Bs[kk][tx * 2];
            acc[0][0] += av.x * bv.x; acc[0][1] += av.x * bv.y;
            acc[1][0] += av.y * bv.x; acc[1][1] += av.y * bv.y;
            acc[2][0] += av.z * bv.x; acc[2][1] += av.z * bv.y;
            acc[3][0] += av.w * bv.x; acc[3][1] += av.w * bv.y;
        }
        __syncthreads();
    }
    float* p = partials + (size_t)ks * B * G4U;
    #pragma unroll
    for (int i = 0; i < 4; i++) {
        int b = ty * 4 + i;
        float2 v; v.x = acc[i][0]; v.y = acc[i][1];
        *(float2*)&p[(size_t)b * G4U + j0 + tx * 2] = v;
    }
}

// ---------- reduce partials + LSTM pointwise ----------
__global__ void k_point2(const float* __restrict__ partials,
                         const float* __restrict__ b_ih, const float* __restrict__ b_hh,
                         float* __restrict__ hid, float* __restrict__ cell,
                         float* __restrict__ outs, int t) {
    int idx = blockIdx.x * 256 + threadIdx.x;  // [0, B*U)
    int b = idx >> 9, u = idx & 511;
    float g[4];
    #pragma unroll
    for (int gi = 0; gi < 4; gi++) {
        int j = gi * 512 + u;
        float s = b_ih[j] + b_hh[j];
        #pragma unroll
        for (int ks = 0; ks < 4; ks++)
            s += partials[((size_t)ks * B + b) * G4U + j];
        g[gi] = s;
    }
    float si = 1.f / (1.f + expf(-g[0]));
    float sf = 1.f / (1.f + expf(-g[1]));
    float tg = tanhf(g[2]);
    float so = 1.f / (1.f + expf(-g[3]));
    float cn = sf * cell[idx] + si * tg;
    float hn = so * tanhf(cn);
    cell[idx] = cn;
    hid[idx] = hn;
    outs[((size_t)b * T + t) * ODIM + u] = hn;
}

// ---------- logits = outs @ W_out^T + b_out : 128x128 tile, 8x8 micro ----------
__global__ __launch_bounds__(256) void k_logits2(const float* __restrict__ A,
                                                 const float* __restrict__ Wo,
                                                 const float* __restrict__ bo,
                                                 float* __restrict__ Cout) {
    __shared__ float As[16][128];
    __shared__ float Bs[16][128];
    int n0 = blockIdx.x * 128;
    int m0 = blockIdx.y * 128;
    int tid = threadIdx.x;
    int tx = tid & 15, ty = tid >> 4;
    int n_local = tx * 8, m_local = ty * 8;
    float acc[8][8] = {};
    for (int k0 = 0; k0 < ODIM; k0 += 16) {
        #pragma unroll
        for (int i = 0; i < 2; i++) {
            int f = tid + i * 256;          // 0..511
            int r = f >> 2, kq = f & 3;
            float4 av = *(const float4*)&A[(size_t)(m0 + r) * ODIM + k0 + kq * 4];
            As[kq * 4 + 0][r] = av.x;
            As[kq * 4 + 1][r] = av.y;
            As[kq * 4 + 2][r] = av.z;
            As[kq * 4 + 3][r] = av.w;
            int n = n0 + r;
            float4 bv;
            if (n < V) bv = *(const float4*)&Wo[(size_t)n * ODIM + k0 + kq * 4];
            else { bv.x = 0.f; bv.y = 0.f; bv.z = 0.f; bv.w = 0.f; }
            Bs[kq * 4 + 0][r] = bv.x;
            Bs[kq * 4 + 1][r] = bv.y;
            Bs[kq * 4 + 2][r] = bv.z;
            Bs[kq * 4 + 3][r] = bv.w;
        }
        __syncthreads();
        #pragma unroll
        for (int kk = 0; kk < 16; kk++) {
            float4 a0 = *(const float4*)&As[kk][m_local];
            float4 a1 = *(const float4*)&As[kk][m_local + 4];
            float4 b0 = *(const float4*)&Bs[kk][n_local];
            float4 b1 = *(const float4*)&Bs[kk][n_local + 4];
            float a_[8] = {a0.x, a0.y, a0.z, a0.w, a1.x, a1.y, a1.z, a1.w};
            float b_[8] = {b0.x, b0.y, b0.z, b0.w, b1.x, b1.y, b1.z, b1.w};
            #pragma unroll
            for (int i = 0; i < 8; i++)
                #pragma unroll
                for (int j = 0; j < 8; j++)
                    acc[i][j] += a_[i] * b_[j];
        }
        __syncthreads();
    }
    #pragma unroll
    for (int q = 0; q < 2; q++) {
        int nb = n0 + n_local + q * 4;
        if (nb + 3 < V) {
            float4 bias4 = *(const float4*)&bo[nb];
            #pragma unroll
            for (int i = 0; i < 8; i++) {
                int m = m0 + m_local + i;
                float4 r4;
                r4.x = acc[i][q * 4 + 0] + bias4.x;
                r4.y = acc[i][q * 4 + 1] + bias4.y;
                r4.z = acc[i][q * 4 + 2] + bias4.z;
                r4.w = acc[i][q * 4 + 3] + bias4.w;
                *(float4*)&Cout[(size_t)m * V + nb] = r4;
            }
        }
    }
}

extern "C" void kernel_launch(void* const* d_in, const int* in_sizes, int n_in,
                              void* d_out, int out_size, void* d_ws, size_t ws_size,
                              hipStream_t stream) {
    const float* img   = (const float*)d_in[0];
    const int*   capix = (const int*)d_in[1];
    const float* W_h0  = (const float*)d_in[2];
    const float* b_h0  = (const float*)d_in[3];
    const float* W_c0  = (const float*)d_in[4];
    const float* b_c0  = (const float*)d_in[5];
    const float* emb   = (const float*)d_in[6];
    const float* W_key = (const float*)d_in[7];
    const float* b_key = (const float*)d_in[8];
    const float* W_ih  = (const float*)d_in[9];
    const float* b_ih  = (const float*)d_in[10];
    const float* W_hh  = (const float*)d_in[11];
    const float* b_hh  = (const float*)d_in[12];
    const float* W_out = (const float*)d_in[13];
    const float* b_out = (const float*)d_in[14];

    float* ws = (float*)d_ws;
    float* partials = ws;                      // 4*B*G4U = 524288  (fm overlaid at base)
    float* fm       = ws;                      // 32768 (dead after k_init, before step 0)
    float* hid      = partials + 524288;       // 32768
    float* cell     = hid + 32768;             // 32768
    float* outs     = cell + 32768;            // B*T*ODIM = 1638400
    float* keysT    = outs + 1638400;          // B*U*HW   = 6422528

    float* logits = (float*)d_out;                    // [B,T,V]
    float* attn   = logits + (size_t)B * T * V;       // [B,T,HW]

    k_mean<<<(B * C) / 4, 256, 0, stream>>>(img, fm);
    k_init<<<(2 * B * U) / 4, 256, 0, stream>>>(fm, W_h0, b_h0, W_c0, b_c0, hid, cell);
    k_keys<<<B * (U / 8), 512, 0, stream>>>(img, W_key, b_key, keysT);
    k_emb<<<B * T, 256, 0, stream>>>(capix, emb, outs);

    for (int t = 0; t < T; t++) {
        k_attn<<<B, 256, 0, stream>>>(hid, keysT, img, outs, attn, t);
        k_gates2<<<dim3(G4U / 32, 4), 256, 0, stream>>>(outs, hid, W_ih, W_hh, partials, t);
        k_point2<<<(B * U) / 256, 256, 0, stream>>>(partials, b_ih, b_hh, hid, cell, outs, t);
    }

    k_logits2<<<dim3((V + 127) / 128, (B * T) / 128), 256, 0, stream>>>(outs, W_out, b_out, logits);
}